// Round 4
// baseline (202.969 us; speedup 1.0000x reference)
//
#include <hip/hip_runtime.h>
#include <math.h>

// Problem constants (fixed by the reference)
#define NSEG 32
#define T_DIM 8
#define F_DIM 32
#define P_DIM 8
#define TF 256           // T_DIM * F_DIM
#define OUT_PER_SEG 2048 // T*P*F
#define EPS_DENOM 1e-16f

#define CHUNK 128
#define K2_THREADS 256
#define NPG (CHUNK / 4)   // 4 waves per block, 32 nodes each

// Tiny MLP: h = elu(pos @ W1 + b1) @ W2 + b2  (per node, P=8 outputs)
__device__ __forceinline__ void compute_h(
    float h[P_DIM], const float* __restrict__ pos, int n,
    const float* __restrict__ W1, const float* __restrict__ b1,
    const float* __restrict__ W2, const float* __restrict__ b2) {
  float p0 = pos[3 * n + 0];
  float p1 = pos[3 * n + 1];
  float p2 = pos[3 * n + 2];
  float a[P_DIM];
#pragma unroll
  for (int p = 0; p < P_DIM; p++) {
    float v = b1[p] + p0 * W1[0 * P_DIM + p] + p1 * W1[1 * P_DIM + p] + p2 * W1[2 * P_DIM + p];
    a[p] = v > 0.f ? v : (__expf(v) - 1.f);  // ELU, alpha=1
  }
#pragma unroll
  for (int p = 0; p < P_DIM; p++) {
    float v = b2[p];
#pragma unroll
    for (int j = 0; j < P_DIM; j++) v += a[j] * W2[j * P_DIM + p];
    h[p] = v;
  }
}

// Kernel 0: zero the output (only ultra-rare middle-run atomics land in it
// before reduce_kernel reads it).
__global__ __launch_bounds__(256) void zero_kernel(float* __restrict__ out, int nf) {
  int i = (blockIdx.x * 256 + threadIdx.x) * 8;
  if (i + 8 <= nf) {
    float4* o = reinterpret_cast<float4*>(out + i);
    float4 z = make_float4(0.f, 0.f, 0.f, 0.f);
    o[0] = z;
    o[1] = z;
  }
}

// per-node FMA into accumulator array A: A[p] (float4 over f) += e[p]*x[n,t,f..f+3]
#define FMA_NODE_TO(A, ii, xv) do {                                            \
    const float4* _wr = reinterpret_cast<const float4*>(&wbuf[(ii)][0]);       \
    float4 _wa = _wr[0], _wb = _wr[1];                                         \
    A[0].x += _wa.x*(xv).x; A[0].y += _wa.x*(xv).y;                            \
    A[0].z += _wa.x*(xv).z; A[0].w += _wa.x*(xv).w;                            \
    A[1].x += _wa.y*(xv).x; A[1].y += _wa.y*(xv).y;                            \
    A[1].z += _wa.y*(xv).z; A[1].w += _wa.y*(xv).w;                            \
    A[2].x += _wa.z*(xv).x; A[2].y += _wa.z*(xv).y;                            \
    A[2].z += _wa.z*(xv).z; A[2].w += _wa.z*(xv).w;                            \
    A[3].x += _wa.w*(xv).x; A[3].y += _wa.w*(xv).y;                            \
    A[3].z += _wa.w*(xv).z; A[3].w += _wa.w*(xv).w;                            \
    A[4].x += _wb.x*(xv).x; A[4].y += _wb.x*(xv).y;                            \
    A[4].z += _wb.x*(xv).z; A[4].w += _wb.x*(xv).w;                            \
    A[5].x += _wb.y*(xv).x; A[5].y += _wb.y*(xv).y;                            \
    A[5].z += _wb.y*(xv).z; A[5].w += _wb.y*(xv).w;                            \
    A[6].x += _wb.z*(xv).x; A[6].y += _wb.z*(xv).y;                            \
    A[6].z += _wb.z*(xv).z; A[6].w += _wb.z*(xv).w;                            \
    A[7].x += _wb.w*(xv).x; A[7].y += _wb.w*(xv).y;                            \
    A[7].z += _wb.w*(xv).z; A[7].w += _wb.w*(xv).w;                            \
  } while (0)

#define LOAD8(dst, i) do {                                                     \
    _Pragma("unroll")                                                          \
    for (int _j = 0; _j < 8; _j++) dst[_j] = xp[(size_t)((i) + _j) * (TF / 4)];\
  } while (0)

#define FMA8(src, i) do {                                                      \
    _Pragma("unroll")                                                          \
    for (int _j = 0; _j < 8; _j++) FMA_NODE_TO(acc, (i) + _j, src[_j]);        \
  } while (0)

// flush accumulators via scalar f32 atomics (ultra-rare middle-run path only)
__device__ __forceinline__ void flush_group(float* __restrict__ out, int sg, int c,
                                            float4 A[P_DIM]) {
  float* o = out + (size_t)sg * OUT_PER_SEG + (c >> 3) * (P_DIM * F_DIM) + (c & 7) * 4;
#pragma unroll
  for (int p = 0; p < P_DIM; p++) {
    float* op = o + p * F_DIM;
    unsafeAtomicAdd(op + 0, A[p].x);
    unsafeAtomicAdd(op + 1, A[p].y);
    unsafeAtomicAdd(op + 2, A[p].z);
    unsafeAtomicAdd(op + 3, A[p].w);
    A[p] = make_float4(0.f, 0.f, 0.f, 0.f);
  }
}

// Kernel 1: block = 128 consecutive nodes, UNNORMALIZED accumulation of
// exp(h[n,p]) * x[n,t,f] (denominator applied in reduce_kernel).
// Phase A: e-weights into LDS. Phase B: 4 waves x 64 float4-columns, each wave
// streams 32 contiguous nodes with a software-pipelined double-buffered
// load schedule (>=8 loads always in flight).
// Every block writes tagged partial slot(s) with plain float4 stores:
//   slot 2b   tagged seg(first node)            (all blocks)
//   slot 2b+1 tagged seg(last node) or -1       (boundary blocks only)
// No atomics except the never-in-practice "whole segment inside one chunk".
__global__ __launch_bounds__(K2_THREADS) void accum_kernel(
    const float* __restrict__ x, const float* __restrict__ pos,
    const int* __restrict__ seg,
    const float* __restrict__ W1, const float* __restrict__ b1,
    const float* __restrict__ W2, const float* __restrict__ b2,
    float* __restrict__ out, float* __restrict__ part,
    int* __restrict__ segtag, int N) {
  __shared__ __align__(16) float wbuf[CHUNK][P_DIM];   // 4 KB
  __shared__ int sbuf[CHUNK];                          // 0.5 KB
  __shared__ float4 facc[P_DIM][4][64];                // 32 KB, [p][group][col]

  int base = blockIdx.x * CHUNK;
  int cnt = N - base;
  if (cnt > CHUNK) cnt = CHUNK;
  int tid = threadIdx.x;

  // Phase A: e[node][p] = exp(h)
  if (tid < cnt) {
    int n = base + tid;
    sbuf[tid] = seg[n];
    float h[P_DIM];
    compute_h(h, pos, n, W1, b1, W2, b2);
#pragma unroll
    for (int p = 0; p < P_DIM; p++)
      wbuf[tid][p] = __expf(h[p]);
  }
  __syncthreads();

  int c = tid & 63;   // column: t = c>>3, f = (c&7)*4
  int g = tid >> 6;   // wave group, owns nodes [g*32, g*32+32)
  int i0 = g * NPG;
  int i1 = i0 + NPG;
  if (i1 > cnt) i1 = cnt;
  if (i0 > cnt) i0 = cnt;

  const float4* xp = reinterpret_cast<const float4*>(x) + (size_t)base * (TF / 4) + c;

  float4 acc[P_DIM];   // accumulates seg == sA (== whole block when uniform)
  float4 accB[P_DIM];  // accumulates seg == sB (boundary blocks)
#pragma unroll
  for (int p = 0; p < P_DIM; p++) {
    acc[p] = make_float4(0.f, 0.f, 0.f, 0.f);
    accB[p] = make_float4(0.f, 0.f, 0.f, 0.f);
  }

  int sA = sbuf[0];
  int sB = sbuf[cnt - 1];
  bool single = (sA == sB);
  if (tid == 0) {
    segtag[2 * blockIdx.x] = sA;
    segtag[2 * blockIdx.x + 1] = single ? -1 : sB;
  }

  if (single) {
    if (i1 - i0 == NPG) {
      // full 32-node straight-line schedule: L L F L F L F F
      float4 xa[8], xb[8];
      LOAD8(xa, i0);
      LOAD8(xb, i0 + 8);
      FMA8(xa, i0);
      LOAD8(xa, i0 + 16);
      FMA8(xb, i0 + 8);
      LOAD8(xb, i0 + 24);
      FMA8(xa, i0 + 16);
      FMA8(xb, i0 + 24);
    } else {
      for (int i = i0; i < i1; ++i) {
        float4 xv = xp[(size_t)i * (TF / 4)];
        FMA_NODE_TO(acc, i, xv);
      }
    }
  } else {
    // Boundary block: accumulate run-wise into acc (seg==sA) / accB (seg==sB);
    // middle runs (complete segment inside the chunk; ~never) via atomics.
    int i = i0;
    while (i < i1) {
      int cur = sbuf[i];
      int j = i + 1;
      while (j < i1 && sbuf[j] == cur) j++;
      if (cur == sA) {
        for (int k = i; k < j; ++k) {
          float4 xv = xp[(size_t)k * (TF / 4)];
          FMA_NODE_TO(acc, k, xv);
        }
      } else if (cur == sB) {
        for (int k = i; k < j; ++k) {
          float4 xv = xp[(size_t)k * (TF / 4)];
          FMA_NODE_TO(accB, k, xv);
        }
      } else {
        float4 accM[P_DIM];
#pragma unroll
        for (int p = 0; p < P_DIM; p++) accM[p] = make_float4(0.f, 0.f, 0.f, 0.f);
        for (int k = i; k < j; ++k) {
          float4 xv = xp[(size_t)k * (TF / 4)];
          FMA_NODE_TO(accM, k, xv);
        }
        flush_group(out, cur, c, accM);
      }
      i = j;
    }
  }

  // Reduction round 0: acc -> part slot 2b (all blocks)
#pragma unroll
  for (int p = 0; p < P_DIM; p++) facc[p][g][c] = acc[p];
  __syncthreads();
  {
    int t = tid >> 5;
    int p = (tid >> 2) & 7;
    int fb = tid & 3;
    int c0 = t * 8 + fb * 2;
    float4 A = facc[p][0][c0];
    float4 B = facc[p][0][c0 + 1];
#pragma unroll
    for (int gg = 1; gg < 4; gg++) {
      float4 a2 = facc[p][gg][c0];
      float4 b2v = facc[p][gg][c0 + 1];
      A.x += a2.x;  A.y += a2.y;  A.z += a2.z;  A.w += a2.w;
      B.x += b2v.x; B.y += b2v.y; B.z += b2v.z; B.w += b2v.w;
    }
    int off = t * (P_DIM * F_DIM) + p * F_DIM + fb * 8;
    float4* po = reinterpret_cast<float4*>(
        part + (size_t)(2 * blockIdx.x) * OUT_PER_SEG + off);
    po[0] = A;
    po[1] = B;
  }

  // Reduction round 1: accB -> part slot 2b+1 (boundary blocks only; uniform branch)
  if (!single) {
    __syncthreads();  // round-0 facc reads complete
#pragma unroll
    for (int p = 0; p < P_DIM; p++) facc[p][g][c] = accB[p];
    __syncthreads();
    int t = tid >> 5;
    int p = (tid >> 2) & 7;
    int fb = tid & 3;
    int c0 = t * 8 + fb * 2;
    float4 A = facc[p][0][c0];
    float4 B = facc[p][0][c0 + 1];
#pragma unroll
    for (int gg = 1; gg < 4; gg++) {
      float4 a2 = facc[p][gg][c0];
      float4 b2v = facc[p][gg][c0 + 1];
      A.x += a2.x;  A.y += a2.y;  A.z += a2.z;  A.w += a2.w;
      B.x += b2v.x; B.y += b2v.y; B.z += b2v.z; B.w += b2v.w;
    }
    int off = t * (P_DIM * F_DIM) + p * F_DIM + fb * 8;
    float4* po = reinterpret_cast<float4*>(
        part + (size_t)(2 * blockIdx.x + 1) * OUT_PER_SEG + off);
    po[0] = A;
    po[1] = B;
  }
}

// Kernel 2: one block per segment. Computes the softmax denominator (sum of
// exp(h) over the segment's nodes), then
//   out = (out_atomic + sum of tagged partial slots) * inv_den.
__global__ __launch_bounds__(256) void reduce_kernel(
    const int* __restrict__ seg, const int* __restrict__ segtag,
    const float* __restrict__ part, const float* __restrict__ pos,
    const float* __restrict__ W1, const float* __restrict__ b1,
    const float* __restrict__ W2, const float* __restrict__ b2,
    float* __restrict__ out, int N) {
  int s = blockIdx.x;
  int tid = threadIdx.x;

  // bounds of segment s (uniform across threads)
  int lo = 0, hi = N;
  while (lo < hi) { int mid = (lo + hi) >> 1; if (seg[mid] < s) lo = mid + 1; else hi = mid; }
  int start = lo;
  lo = start; hi = N;
  while (lo < hi) { int mid = (lo + hi) >> 1; if (seg[mid] < s + 1) lo = mid + 1; else hi = mid; }
  int end = lo;
  if (start >= end) return;  // empty segment: out stays zero

  // denominator: sum of exp(h) over the segment's nodes
  float lsum[P_DIM];
#pragma unroll
  for (int p = 0; p < P_DIM; p++) lsum[p] = 0.f;
  for (int i = start + tid; i < end; i += 256) {
    float h[P_DIM];
    compute_h(h, pos, i, W1, b1, W2, b2);
#pragma unroll
    for (int p = 0; p < P_DIM; p++) lsum[p] += __expf(h[p]);
  }
#pragma unroll
  for (int off = 32; off >= 1; off >>= 1)
#pragma unroll
    for (int p = 0; p < P_DIM; p++)
      lsum[p] += __shfl_down(lsum[p], off, 64);

  __shared__ float wred[P_DIM][4];
  __shared__ float invd[P_DIM];
  int wid = tid >> 6, lane = tid & 63;
  if (lane == 0) {
#pragma unroll
    for (int p = 0; p < P_DIM; p++) wred[p][wid] = lsum[p];
  }
  __syncthreads();
  if (tid < P_DIM) {
    float ss = wred[tid][0] + wred[tid][1] + wred[tid][2] + wred[tid][3];
    invd[tid] = 1.f / (ss + EPS_DENOM);
  }
  __syncthreads();

  // combine tagged partials + (rare) atomic contributions, scale, store
  int b0 = start / CHUNK;
  int b1i = (end - 1) / CHUNK;
  int p = (tid >> 2) & 7;  // out layout: [t][p][f], tid*8 = t*256 + p*32 + fb*8
  float s0 = invd[p];

  float* o = out + (size_t)s * OUT_PER_SEG + tid * 8;
  float4 A = reinterpret_cast<float4*>(o)[0];
  float4 B = reinterpret_cast<float4*>(o)[1];
  for (int b = b0; b <= b1i; b++) {
#pragma unroll
    for (int hslot = 0; hslot < 2; hslot++) {
      if (segtag[2 * b + hslot] == s) {
        const float4* pp = reinterpret_cast<const float4*>(
            part + (size_t)(2 * b + hslot) * OUT_PER_SEG + tid * 8);
        float4 a2 = pp[0], b2v = pp[1];
        A.x += a2.x;  A.y += a2.y;  A.z += a2.z;  A.w += a2.w;
        B.x += b2v.x; B.y += b2v.y; B.z += b2v.z; B.w += b2v.w;
      }
    }
  }
  A.x *= s0; A.y *= s0; A.z *= s0; A.w *= s0;
  B.x *= s0; B.y *= s0; B.z *= s0; B.w *= s0;
  reinterpret_cast<float4*>(o)[0] = A;
  reinterpret_cast<float4*>(o)[1] = B;
}

extern "C" void kernel_launch(void* const* d_in, const int* in_sizes, int n_in,
                              void* d_out, int out_size, void* d_ws, size_t ws_size,
                              hipStream_t stream) {
  const float* pos = (const float*)d_in[0];
  const float* x   = (const float*)d_in[1];
  const int*   seg = (const int*)d_in[2];
  const float* W1  = (const float*)d_in[3];
  const float* b1  = (const float*)d_in[4];
  const float* W2  = (const float*)d_in[5];
  const float* b2  = (const float*)d_in[6];
  float* out = (float*)d_out;
  int N = in_sizes[2];
  int nblk = (N + CHUNK - 1) / CHUNK;

  // workspace layout: segtag [2*nblk i32] | partials [2*nblk*2048 f32]
  char* ws = (char*)d_ws;
  size_t part_off = ((size_t)2 * nblk * 4 + 255) & ~(size_t)255;
  int* segtag = (int*)ws;
  float* part = (float*)(ws + part_off);

  int zblk = (out_size / 8 + 255) / 256;
  zero_kernel<<<zblk, 256, 0, stream>>>(out, out_size);

  accum_kernel<<<nblk, K2_THREADS, 0, stream>>>(
      x, pos, seg, W1, b1, W2, b2, out, part, segtag, N);

  reduce_kernel<<<NSEG, 256, 0, stream>>>(
      seg, segtag, part, pos, W1, b1, W2, b2, out, N);
}